// Round 8
// baseline (539.382 us; speedup 1.0000x reference)
//
#include <hip/hip_runtime.h>
#include <math.h>

// ---------------- problem constants ----------------
#define MB    512
#define FS    24
#define QDIM  11
#define OBJ   25
#define HID   256

typedef unsigned short u16;
typedef __attribute__((ext_vector_type(8))) __bf16 bf16x8;
typedef __attribute__((ext_vector_type(4))) float f32x4;

__device__ __forceinline__ float bf2f(u16 h) {
    return __uint_as_float(((unsigned int)h) << 16);
}
__device__ __forceinline__ u16 f2bf(float f) {
    unsigned int u = __float_as_uint(f);
    return (u16)((u + 0x7FFFu + ((u >> 16) & 1u)) >> 16);
}
// pack 2 f32 -> 2 bf16 (truncate) in one v_perm_b32
__device__ __forceinline__ unsigned pk2bf(float hi, float lo) {
    return __builtin_amdgcn_perm(__float_as_uint(hi), __float_as_uint(lo), 0x07060302u);
}

// ---------------- combined prep ----------------
// blocks 0..767: wfrag for g-GEMMs (196608 u16)
// blocks 768..878: wt1 (648 f32) + wcfrag (27648 u16)
__global__ __launch_bounds__(256) void prep_all(
    const float* __restrict__ g2w, const float* __restrict__ g3w,
    const float* __restrict__ g4w, u16* __restrict__ wfrag,
    const float* __restrict__ cw1, const float* __restrict__ cw2,
    const float* __restrict__ cw3, const float* __restrict__ cw4,
    float* __restrict__ wt1, u16* __restrict__ wcfrag)
{
    if (blockIdx.x < 768) {
        int idx = blockIdx.x * 256 + threadIdx.x;   // 196608 total
        int jj = idx & 7;
        int lane = (idx >> 3) & 63;
        int tn = (idx >> 9) & 15;
        int c = (idx >> 13) & 7;
        int l = idx >> 16;
        const float* W = (l == 0) ? g2w : ((l == 1) ? g3w : g4w);
        int n = tn * 16 + (lane & 15);
        int k = c * 32 + (lane >> 4) * 8 + jj;
        wfrag[idx] = f2bf(W[n * 256 + k]);
    } else {
        int idx = (blockIdx.x - 768) * 256 + threadIdx.x;
        if (idx < 648) {
            int k = idx / 24, oc = idx % 24;
            wt1[idx] = cw1[oc * 27 + k];
        } else if (idx < 648 + 27648) {
            int t = idx - 648;
            int l = t / 9216, r = t % 9216;
            int cell = r / 1024, rr = r % 1024;
            int o = rr / 512, q = rr % 512;
            int lane = q / 8, j = q % 8;
            int oc = o * 16 + (lane & 15);
            int ic = (lane >> 4) * 8 + j;
            const float* w = (l == 0) ? cw2 : ((l == 1) ? cw3 : cw4);
            u16 v = 0;
            if (oc < 24 && ic < 24) v = f2bf(w[oc * 216 + ic * 9 + cell]);
            wcfrag[t] = v;
        }
    }
}

// ---------------- conv1: img NCHW -> y1 channel-last, LDS weights, + fused BN stats ----------------
__global__ __launch_bounds__(256) void conv1_t(
    const float* __restrict__ img, const float* __restrict__ wt1,
    const float* __restrict__ bias, float* __restrict__ yout,
    float* __restrict__ stats)
{
    __shared__ float tile[3 * 21 * 85];
    __shared__ float wS[648];
    __shared__ float part[48];
    const int tid = threadIdx.x;
    const int b   = blockIdx.x >> 2;
    const int y0  = (blockIdx.x & 3) * 10;
    const int iy_base = 2 * y0 - 1;
    for (int e = tid; e < 648; e += 256) wS[e] = wt1[e];
    for (int e = tid; e < 3 * 21 * 85; e += 256) {
        int ixt = e % 85; int rem = e / 85;
        int iyl = rem % 21; int ic = rem / 21;
        int iy = iy_base + iyl, ix = ixt - 1;
        float v = 0.f;
        if ((unsigned)iy < 80u && (unsigned)ix < 80u)
            v = img[((size_t)(b * 3 + ic) * 80 + iy) * 80 + ix];
        tile[e] = v;
    }
    if (tid < 48) part[tid] = 0.f;
    __syncthreads();

    float rsum[24], rsq[24];
#pragma unroll
    for (int oc = 0; oc < 24; oc++) { rsum[oc] = 0.f; rsq[oc] = 0.f; }

#pragma unroll 1
    for (int pp = 0; pp < 2; pp++) {
        const int pxl = tid + pp * 256;
        const bool active = pxl < 400;
        const int pxc = active ? pxl : 0;
        const int yl = pxc / 40, x = pxc % 40;
        float acc[24];
#pragma unroll
        for (int oc = 0; oc < 24; oc++) acc[oc] = bias[oc];
#pragma unroll 1
        for (int ic = 0; ic < 3; ic++) {
#pragma unroll 1
            for (int ky = 0; ky < 3; ky++) {
#pragma unroll 1
                for (int kx = 0; kx < 3; kx++) {
                    const int k = (ic * 3 + ky) * 3 + kx;
                    float xin = tile[ic * 1785 + (2 * yl + ky) * 85 + (2 * x + kx)];
                    const float4* wrow = (const float4*)&wS[k * 24];
#pragma unroll
                    for (int g = 0; g < 6; g++) {
                        float4 wv = wrow[g];
                        acc[g * 4 + 0] = fmaf(xin, wv.x, acc[g * 4 + 0]);
                        acc[g * 4 + 1] = fmaf(xin, wv.y, acc[g * 4 + 1]);
                        acc[g * 4 + 2] = fmaf(xin, wv.z, acc[g * 4 + 2]);
                        acc[g * 4 + 3] = fmaf(xin, wv.w, acc[g * 4 + 3]);
                    }
                }
            }
        }
#pragma unroll
        for (int oc = 0; oc < 24; oc++)
            acc[oc] = active ? fmaxf(acc[oc], 0.f) : 0.f;
        if (active) {
            float* op = &yout[((size_t)b * 1600 + (y0 + yl) * 40 + x) * 24];
#pragma unroll
            for (int g = 0; g < 6; g++)
                *(float4*)&op[g * 4] = make_float4(acc[g * 4], acc[g * 4 + 1],
                                                   acc[g * 4 + 2], acc[g * 4 + 3]);
        }
#pragma unroll
        for (int oc = 0; oc < 24; oc++) {
            rsum[oc] += acc[oc];
            rsq[oc]  += acc[oc] * acc[oc];
        }
    }
#pragma unroll
    for (int oc = 0; oc < 24; oc++) {
        float a = rsum[oc], q = rsq[oc];
#pragma unroll
        for (int off = 1; off < 64; off <<= 1) {
            a += __shfl_xor(a, off, 64);
            q += __shfl_xor(q, off, 64);
        }
        if ((tid & 63) == 0) { atomicAdd(&part[oc], a); atomicAdd(&part[24 + oc], q); }
    }
    __syncthreads();
    if (tid < 48) atomicAdd(&stats[tid], part[tid]);
}

// ---------------- MFMA conv 24->24 stride2 pad1 ----------------
template<int HIN, int HOUT, int YT, int MT>
__global__ __launch_bounds__(256) void convM(
    const float* __restrict__ yin,
    const float* __restrict__ stp, const float* __restrict__ gam,
    const float* __restrict__ bet, float invN,
    const u16* __restrict__ wcf_g,
    const float* __restrict__ bias,
    float* __restrict__ yout, float* __restrict__ stats)
{
    constexpr int ROWS = 2 * YT + 1;
    constexpr int R    = 2 * HOUT + 1;
    constexpr int POS  = ROWS * R;
    constexpr int NPX  = HOUT * HOUT;
    constexpr int NPXB = YT * HOUT;
    constexpr int TILES = HOUT / YT;
    constexpr int MTPW = (MT + 3) / 4;
    __shared__ __align__(16) u16 tile[POS * 24 + 16];
    __shared__ float scW[48];
    __shared__ float part[48];
    const int tid  = threadIdx.x;
    const int b    = (TILES == 1) ? blockIdx.x : (int)(blockIdx.x / TILES);
    const int y0   = (TILES == 1) ? 0 : (int)(blockIdx.x % TILES) * YT;
    const int lane = tid & 63, wave = tid >> 6;
    const int r16  = lane & 15, quad = lane >> 4;

    if (tid < 24) {
        float m   = stp[tid] * invN;
        float var = stp[24 + tid] * invN - m * m;
        float inv = gam[tid] * rsqrtf(var + 1e-5f);
        scW[tid]      = inv;
        scW[24 + tid] = bet[tid] - m * inv;
    }
    if (tid < 48) part[tid] = 0.f;

    bf16x8 wcf[9][2];
#pragma unroll
    for (int c = 0; c < 9; c++)
#pragma unroll
        for (int o = 0; o < 2; o++)
            wcf[c][o] = *(const bf16x8*)&wcf_g[((c * 2 + o) * 64 + lane) * 8];

    __syncthreads();

    const int iy_base = 2 * y0 - 1;
    for (int p = tid; p < POS; p += 256) {
        int iyl = p / R, ixt = p % R;
        int iy = iy_base + iyl, ix = ixt - 1;
        unsigned w[12];
        if ((unsigned)iy < (unsigned)HIN && (unsigned)ix < (unsigned)HIN) {
            const float* ip = &yin[((size_t)b * HIN * HIN + iy * HIN + ix) * 24];
            float e[24];
#pragma unroll
            for (int c = 0; c < 24; c++)
                e[c] = fmaf(ip[c], scW[c], scW[24 + c]);
#pragma unroll
            for (int i = 0; i < 12; i++)
                w[i] = pk2bf(e[2 * i + 1], e[2 * i]);
        } else {
#pragma unroll
            for (int i = 0; i < 12; i++) w[i] = 0;
        }
#pragma unroll
        for (int g = 0; g < 3; g++)
            *(uint4*)&tile[p * 24 + g * 8] =
                make_uint4(w[g * 4], w[g * 4 + 1], w[g * 4 + 2], w[g * 4 + 3]);
    }
    __syncthreads();

    f32x4 acc[MTPW][2];
#pragma unroll
    for (int t = 0; t < MTPW; t++) {
        acc[t][0] = (f32x4)(0.f);
        acc[t][1] = (f32x4)(0.f);
    }

    int baseT[MTPW];
#pragma unroll
    for (int t = 0; t < MTPW; t++) {
        int mt = wave + t * 4;
        int pxl = mt * 16 + r16;
        if (pxl > NPXB - 1) pxl = NPXB - 1;
        baseT[t] = ((2 * (pxl / HOUT)) * R + 2 * (pxl % HOUT)) * 24 + quad * 8;
    }

#pragma unroll
    for (int ky = 0; ky < 3; ky++) {
#pragma unroll
        for (int kx = 0; kx < 3; kx++) {
            const int cell = ky * 3 + kx;
            const int coff = (ky * R + kx) * 24;
            bf16x8 xf[MTPW];
#pragma unroll
            for (int t = 0; t < MTPW; t++) {
                int mt = wave + t * 4;
                uint4 tmp = make_uint4(0, 0, 0, 0);
                if (mt < MT && quad < 3)
                    tmp = *(const uint4*)&tile[baseT[t] + coff];
                xf[t] = *(bf16x8*)&tmp;
            }
#pragma unroll
            for (int t = 0; t < MTPW; t++) {
                int mt = wave + t * 4;
                if (mt < MT) {
                    acc[t][0] = __builtin_amdgcn_mfma_f32_16x16x32_bf16(
                        wcf[cell][0], xf[t], acc[t][0], 0, 0, 0);
                    acc[t][1] = __builtin_amdgcn_mfma_f32_16x16x32_bf16(
                        wcf[cell][1], xf[t], acc[t][1], 0, 0, 0);
                }
            }
        }
    }

    float ss[2][4], qq[2][4];
#pragma unroll
    for (int o = 0; o < 2; o++)
#pragma unroll
        for (int r = 0; r < 4; r++) { ss[o][r] = 0.f; qq[o][r] = 0.f; }

#pragma unroll
    for (int t = 0; t < MTPW; t++) {
        int mt = wave + t * 4;
        if (mt >= MT) continue;
        int pxl = mt * 16 + r16;
        bool pv = pxl < NPXB;
        int pxi = y0 * HOUT + pxl;
#pragma unroll
        for (int o = 0; o < 2; o++) {
            int ocb = o * 16 + quad * 4;
            if (pv && ocb < 24) {
                float4 bb = *(const float4*)&bias[ocb];
                float v0 = fmaxf(acc[t][o][0] + bb.x, 0.f);
                float v1 = fmaxf(acc[t][o][1] + bb.y, 0.f);
                float v2 = fmaxf(acc[t][o][2] + bb.z, 0.f);
                float v3 = fmaxf(acc[t][o][3] + bb.w, 0.f);
                *(float4*)&yout[((size_t)b * NPX + pxi) * 24 + ocb] =
                    make_float4(v0, v1, v2, v3);
                ss[o][0] += v0; qq[o][0] += v0 * v0;
                ss[o][1] += v1; qq[o][1] += v1 * v1;
                ss[o][2] += v2; qq[o][2] += v2 * v2;
                ss[o][3] += v3; qq[o][3] += v3 * v3;
            }
        }
    }
#pragma unroll
    for (int o = 0; o < 2; o++) {
        int ocb = o * 16 + quad * 4;
#pragma unroll
        for (int r = 0; r < 4; r++) {
            float a = ss[o][r], q = qq[o][r];
            a += __shfl_xor(a, 1, 64); q += __shfl_xor(q, 1, 64);
            a += __shfl_xor(a, 2, 64); q += __shfl_xor(q, 2, 64);
            a += __shfl_xor(a, 4, 64); q += __shfl_xor(q, 4, 64);
            a += __shfl_xor(a, 8, 64); q += __shfl_xor(q, 8, 64);
            if (r16 == 0 && ocb < 24) {
                atomicAdd(&part[ocb + r], a);
                atomicAdd(&part[24 + ocb + r], q);
            }
        }
    }
    __syncthreads();
    if (tid < 48) atomicAdd(&stats[tid], part[tid]);
}

// ---------------- u/v precompute for g1 (f32 output), BN4 computed in-kernel ----------------
__global__ __launch_bounds__(256) void uv_kernel(
    const float* __restrict__ y4t,
    const float* __restrict__ stp, const float* __restrict__ gam,
    const float* __restrict__ bet, float invN,
    const float* __restrict__ qst, const float* __restrict__ g1w,
    const float* __restrict__ g1b, float* __restrict__ u, float* __restrict__ v)
{
    int b = blockIdx.x, tid = threadIdx.x;
    __shared__ float xf[650];
    __shared__ float qv[11];
    __shared__ float scW[48];
    if (tid < 24) {
        float m   = stp[tid] * invN;
        float var = stp[24 + tid] * invN - m * m;
        float inv = gam[tid] * rsqrtf(var + 1e-5f);
        scW[tid]      = inv;
        scW[24 + tid] = bet[tid] - m * inv;
    }
    __syncthreads();
    for (int e = tid; e < 650; e += 256) {
        int o = e / 26, c = e % 26;
        float val;
        if (c < 24)      val = y4t[b * 600 + o * 24 + c] * scW[c] + scW[24 + c];
        else if (c == 24) val = (float)(o / 5 - 2) * 0.5f;
        else              val = (float)(o % 5 - 2) * 0.5f;
        xf[e] = val;
    }
    if (tid < 11) qv[tid] = qst[tid * MB + b];
    __syncthreads();
    const int n = tid;
    float wrow[63];
#pragma unroll
    for (int c = 0; c < 63; c++) wrow[c] = g1w[n * 63 + c];
    float qsum = g1b[n];
#pragma unroll
    for (int j = 0; j < 11; j++) qsum += wrow[52 + j] * qv[j];
    for (int o = 0; o < 25; o++) {
        float uu = 0.f, vv = qsum;
#pragma unroll
        for (int c = 0; c < 26; c++) {
            uu += wrow[c]      * xf[o * 26 + c];
            vv += wrow[26 + c] * xf[o * 26 + c];
        }
        u[(b * 25 + o) * 256 + n] = uu;
        v[(b * 25 + o) * 256 + n] = vv;
    }
}

// ---------------- fused g2/g3/g4 + pair-sum, bf16 MFMA ----------------
// VALU-slim: u/v read as f32, h packed to bf16 via v_perm (truncate); ping-pong
// weight buffers (no per-chunk reg copies). 4 waves, wave tile 128m x 64n.
__global__ __launch_bounds__(256, 2) void g_fused(
    const float* __restrict__ u_f, const float* __restrict__ v_f,
    const u16* __restrict__ wfrag,
    const float* __restrict__ b2, const float* __restrict__ b3, const float* __restrict__ b4,
    float* __restrict__ xg)
{
    __shared__ u16 hS[32768];   // 128 x 256 halves, XOR-swizzled 8-half granules
    const int tid  = threadIdx.x;
    const int b    = blockIdx.x / 5;
    const int p0   = (blockIdx.x % 5) * 128;
    const int lane = tid & 63, wave = tid >> 6;
    const int r16  = lane & 15, sub = lane >> 4;
    const int n0w  = wave * 64;

    const u16* wfL = wfrag + (size_t)(wave * 4) * 512 + (size_t)lane * 8;

    // ---- stage h1 = relu(u[oi] + v[ok]) into hS (f32 in, perm-pack out) ----
    {
        const int m = tid & 127, half = tid >> 7;
        const int p = p0 + m;
        if (p < 625) {
            const int oi = p % 25, ok = p / 25;
            const float4* up = (const float4*)(u_f + (size_t)(b * 25 + oi) * 256);
            const float4* vp = (const float4*)(v_f + (size_t)(b * 25 + ok) * 256);
#pragma unroll
            for (int gi = 0; gi < 16; gi++) {
                const int g = half * 16 + gi;
                float4 ua = up[g * 2],     va = vp[g * 2];
                float4 ub = up[g * 2 + 1], vb = vp[g * 2 + 1];
                float f0 = fmaxf(ua.x + va.x, 0.f), f1 = fmaxf(ua.y + va.y, 0.f);
                float f2 = fmaxf(ua.z + va.z, 0.f), f3 = fmaxf(ua.w + va.w, 0.f);
                float f4 = fmaxf(ub.x + vb.x, 0.f), f5 = fmaxf(ub.y + vb.y, 0.f);
                float f6 = fmaxf(ub.z + vb.z, 0.f), f7 = fmaxf(ub.w + vb.w, 0.f);
                *(uint4*)&hS[m * 256 + ((g ^ (m & 7)) * 8)] =
                    make_uint4(pk2bf(f1, f0), pk2bf(f3, f2), pk2bf(f5, f4), pk2bf(f7, f6));
            }
        } else {
            uint4 z = make_uint4(0, 0, 0, 0);
#pragma unroll
            for (int gi = 0; gi < 16; gi++) {
                const int g = half * 16 + gi;
                *(uint4*)&hS[m * 256 + ((g ^ (m & 7)) * 8)] = z;
            }
        }
    }

#pragma unroll 1
    for (int l = 0; l < 3; l++) {
        f32x4 acc[8][4];
#pragma unroll
        for (int tm = 0; tm < 8; tm++)
#pragma unroll
            for (int tn = 0; tn < 4; tn++)
                acc[tm][tn] = (f32x4)(0.f);

        bf16x8 wA[4], wB[4];
#pragma unroll
        for (int tn = 0; tn < 4; tn++)
            wA[tn] = *(const bf16x8*)&wfL[((size_t)(l * 8) * 16 + tn) * 512];

        __syncthreads();   // hS ready

#pragma unroll 1
        for (int kb = 0; kb < 8; kb += 2) {
            const int s = l * 8 + kb;
            // prefetch chunk kb+1 into wB
            if (s + 1 < 24) {
#pragma unroll
                for (int tn = 0; tn < 4; tn++)
                    wB[tn] = *(const bf16x8*)&wfL[((size_t)(s + 1) * 16 + tn) * 512];
            }
            {
                bf16x8 bfr[8];
                const int g = kb * 4 + sub;
#pragma unroll
                for (int tm = 0; tm < 8; tm++) {
                    const int m = tm * 16 + r16;
                    bfr[tm] = *(const bf16x8*)&hS[m * 256 + ((g ^ (m & 7)) * 8)];
                }
#pragma unroll
                for (int tm = 0; tm < 8; tm++)
#pragma unroll
                    for (int tn = 0; tn < 4; tn++)
                        acc[tm][tn] = __builtin_amdgcn_mfma_f32_16x16x32_bf16(
                            wA[tn], bfr[tm], acc[tm][tn], 0, 0, 0);
            }
            // prefetch chunk kb+2 into wA
            if (s + 2 < 24) {
#pragma unroll
                for (int tn = 0; tn < 4; tn++)
                    wA[tn] = *(const bf16x8*)&wfL[((size_t)(s + 2) * 16 + tn) * 512];
            }
            {
                bf16x8 bfr[8];
                const int g = (kb + 1) * 4 + sub;
#pragma unroll
                for (int tm = 0; tm < 8; tm++) {
                    const int m = tm * 16 + r16;
                    bfr[tm] = *(const bf16x8*)&hS[m * 256 + ((g ^ (m & 7)) * 8)];
                }
#pragma unroll
                for (int tm = 0; tm < 8; tm++)
#pragma unroll
                    for (int tn = 0; tn < 4; tn++)
                        acc[tm][tn] = __builtin_amdgcn_mfma_f32_16x16x32_bf16(
                            wB[tn], bfr[tm], acc[tm][tn], 0, 0, 0);
            }
        }
        __syncthreads();   // all hS reads complete before overwrite

        const float* bl = (l == 0) ? b2 : ((l == 1) ? b3 : b4);
        if (l < 2) {
#pragma unroll
            for (int tn = 0; tn < 4; tn++) {
                const int n0 = n0w + tn * 16 + sub * 4;
                const float4 bb = *(const float4*)&bl[n0];
                const int gg = n0 >> 3;
                const int sh = (sub & 1) * 4;
#pragma unroll
                for (int tm = 0; tm < 8; tm++) {
                    const int m = tm * 16 + r16;
                    float v0 = fmaxf(acc[tm][tn][0] + bb.x, 0.f);
                    float v1 = fmaxf(acc[tm][tn][1] + bb.y, 0.f);
                    float v2 = fmaxf(acc[tm][tn][2] + bb.z, 0.f);
                    float v3 = fmaxf(acc[tm][tn][3] + bb.w, 0.f);
                    uint2 pw = make_uint2(pk2bf(v1, v0), pk2bf(v3, v2));
                    *(uint2*)&hS[m * 256 + ((gg ^ (m & 7)) * 8) + sh] = pw;
                }
            }
        } else {
            float s[4][4];
#pragma unroll
            for (int tn = 0; tn < 4; tn++)
#pragma unroll
                for (int r = 0; r < 4; r++) s[tn][r] = 0.f;
#pragma unroll
            for (int tn = 0; tn < 4; tn++) {
                const int n0 = n0w + tn * 16 + sub * 4;
                const float4 bb = *(const float4*)&bl[n0];
#pragma unroll
                for (int tm = 0; tm < 8; tm++) {
                    const int m = tm * 16 + r16;
                    if (p0 + m < 625) {
                        s[tn][0] += fmaxf(acc[tm][tn][0] + bb.x, 0.f);
                        s[tn][1] += fmaxf(acc[tm][tn][1] + bb.y, 0.f);
                        s[tn][2] += fmaxf(acc[tm][tn][2] + bb.z, 0.f);
                        s[tn][3] += fmaxf(acc[tm][tn][3] + bb.w, 0.f);
                    }
                }
            }
#pragma unroll
            for (int tn = 0; tn < 4; tn++)
#pragma unroll
                for (int r = 0; r < 4; r++) {
                    float v = s[tn][r];
                    v += __shfl_xor(v, 1, 64);
                    v += __shfl_xor(v, 2, 64);
                    v += __shfl_xor(v, 4, 64);
                    v += __shfl_xor(v, 8, 64);
                    if (r16 == 0)
                        atomicAdd(&xg[b * 256 + n0w + tn * 16 + sub * 4 + r], v);
                }
        }
    }
}

// ---------------- f1 -> fc2 -> fc3 -> log_softmax ----------------
__global__ __launch_bounds__(256) void f_fused(
    const float* __restrict__ xg,
    const float* __restrict__ f1w, const float* __restrict__ f1b,
    const float* __restrict__ fc2w, const float* __restrict__ fc2b,
    const float* __restrict__ fc3w, const float* __restrict__ fc3b,
    float* __restrict__ out)
{
    const int b = blockIdx.x, tid = threadIdx.x;
    __shared__ float xa[256], xb[256], lg[10], red[2];
    xa[tid] = xg[b * 256 + tid];
    __syncthreads();
    {
        const float4* wr = (const float4*)(f1w + (size_t)tid * 256);
        float a = f1b[tid];
#pragma unroll
        for (int k4 = 0; k4 < 64; k4++) {
            float4 w4 = wr[k4];
            a += w4.x * xa[k4 * 4 + 0] + w4.y * xa[k4 * 4 + 1]
               + w4.z * xa[k4 * 4 + 2] + w4.w * xa[k4 * 4 + 3];
        }
        xb[tid] = a > 0.f ? a : 0.f;
    }
    __syncthreads();
    {
        const float4* wr = (const float4*)(fc2w + (size_t)tid * 256);
        float a = fc2b[tid];
#pragma unroll
        for (int k4 = 0; k4 < 64; k4++) {
            float4 w4 = wr[k4];
            a += w4.x * xb[k4 * 4 + 0] + w4.y * xb[k4 * 4 + 1]
               + w4.z * xb[k4 * 4 + 2] + w4.w * xb[k4 * 4 + 3];
        }
        __syncthreads();
        xa[tid] = a > 0.f ? a : 0.f;
    }
    __syncthreads();
    if (tid < 10) {
        const float4* wr = (const float4*)(fc3w + (size_t)tid * 256);
        float a = fc3b[tid];
#pragma unroll
        for (int k4 = 0; k4 < 64; k4++) {
            float4 w4 = wr[k4];
            a += w4.x * xa[k4 * 4 + 0] + w4.y * xa[k4 * 4 + 1]
               + w4.z * xa[k4 * 4 + 2] + w4.w * xa[k4 * 4 + 3];
        }
        lg[tid] = a;
    }
    __syncthreads();
    if (tid == 0) {
        float mx = lg[0];
        for (int o = 1; o < 10; o++) mx = lg[o] > mx ? lg[o] : mx;
        float ssum = 0.f;
        for (int o = 0; o < 10; o++) ssum += expf(lg[o] - mx);
        red[0] = mx;
        red[1] = logf(ssum);
    }
    __syncthreads();
    if (tid < 10) out[b * 10 + tid] = lg[tid] - red[0] - red[1];
}

// ---------------- launcher ----------------
extern "C" void kernel_launch(void* const* d_in, const int* in_sizes, int n_in,
                              void* d_out, int out_size, void* d_ws, size_t ws_size,
                              hipStream_t stream)
{
    const float* img  = (const float*)d_in[0];
    const float* qst  = (const float*)d_in[1];
    const float* cw1  = (const float*)d_in[2];
    const float* cb1  = (const float*)d_in[3];
    const float* bg1  = (const float*)d_in[4];
    const float* bb1  = (const float*)d_in[5];
    const float* cw2  = (const float*)d_in[6];
    const float* cb2  = (const float*)d_in[7];
    const float* bg2  = (const float*)d_in[8];
    const float* bb2  = (const float*)d_in[9];
    const float* cw3  = (const float*)d_in[10];
    const float* cb3  = (const float*)d_in[11];
    const float* bg3  = (const float*)d_in[12];
    const float* bb3  = (const float*)d_in[13];
    const float* cw4  = (const float*)d_in[14];
    const float* cb4  = (const float*)d_in[15];
    const float* bg4  = (const float*)d_in[16];
    const float* bb4  = (const float*)d_in[17];
    const float* g1w  = (const float*)d_in[18];
    const float* g1b  = (const float*)d_in[19];
    const float* g2w  = (const float*)d_in[20];
    const float* g2b  = (const float*)d_in[21];
    const float* g3w  = (const float*)d_in[22];
    const float* g3b  = (const float*)d_in[23];
    const float* g4w  = (const float*)d_in[24];
    const float* g4b  = (const float*)d_in[25];
    const float* f1w  = (const float*)d_in[26];
    const float* f1b  = (const float*)d_in[27];
    const float* fc2w = (const float*)d_in[28];
    const float* fc2b = (const float*)d_in[29];
    const float* fc3w = (const float*)d_in[30];
    const float* fc3b = (const float*)d_in[31];
    float* out = (float*)d_out;

    float* ws    = (float*)d_ws;
    float* stats = ws;                        // 192
    float* xg    = ws + 192;                  // 131072
    u16*   wfrag = (u16*)(ws + 131456);       // 196608 u16 -> ends 229760
    float* wt1   = ws + 229760;               // 648
    u16*   wcfrag = (u16*)(ws + 230408);      // 27648 u16 -> ends 244232
    float* y1    = ws + 328064;               // 19,660,800  [b][1600][24]
    float* y2    = ws + 19988864;             // 4,915,200   [b][400][24]
    float* y3    = ws + 24904064;             // 1,228,800   [b][100][24]
    float* y4    = ws + 26132864;             // 307,200     [b][25][24]
    float* u_f   = ws + 26440064;             // 3,276,800 f32
    float* v_f   = ws + 29716864;             // 3,276,800 f32 (end 32,993,664)

    hipMemsetAsync(stats, 0, (size_t)131264 * sizeof(float), stream);

    prep_all<<<879, 256, 0, stream>>>(g2w, g3w, g4w, wfrag,
                                      cw1, cw2, cw3, cw4, wt1, wcfrag);

    conv1_t<<<2048, 256, 0, stream>>>(img, wt1, cb1, y1, stats);

    convM<40, 20, 4, 5><<<2560, 256, 0, stream>>>(
        y1, stats, bg1, bb1, 1.f / 819200.f, wcfrag, cb2, y2, stats + 48);
    convM<20, 10, 10, 7><<<512, 256, 0, stream>>>(
        y2, stats + 48, bg2, bb2, 1.f / 204800.f, wcfrag + 9216, cb3, y3, stats + 96);
    convM<10, 5, 5, 2><<<512, 256, 0, stream>>>(
        y3, stats + 96, bg3, bb3, 1.f / 51200.f, wcfrag + 18432, cb4, y4, stats + 144);

    uv_kernel<<<512, 256, 0, stream>>>(y4, stats + 144, bg4, bb4, 1.f / 12800.f,
                                       qst, g1w, g1b, u_f, v_f);

    g_fused<<<2560, 256, 0, stream>>>(u_f, v_f, wfrag, g2b, g3b, g4b, xg);

    f_fused<<<512, 256, 0, stream>>>(xg, f1w, f1b, fc2w, fc2b, fc3w, fc3b, out);
}

// Round 9
// 537.010 us; speedup vs baseline: 1.0044x; 1.0044x over previous
//
#include <hip/hip_runtime.h>
#include <math.h>

// ---------------- problem constants ----------------
#define MB    512
#define FS    24
#define QDIM  11
#define OBJ   25
#define HID   256

typedef unsigned short u16;
typedef __attribute__((ext_vector_type(8))) __bf16 bf16x8;
typedef __attribute__((ext_vector_type(4))) float f32x4;

__device__ __forceinline__ float bf2f(u16 h) {
    return __uint_as_float(((unsigned int)h) << 16);
}
__device__ __forceinline__ u16 f2bf(float f) {
    unsigned int u = __float_as_uint(f);
    return (u16)((u + 0x7FFFu + ((u >> 16) & 1u)) >> 16);
}
// pack 2 f32 -> 2 bf16 (truncate) in one v_perm_b32
__device__ __forceinline__ unsigned pk2bf(float hi, float lo) {
    return __builtin_amdgcn_perm(__float_as_uint(hi), __float_as_uint(lo), 0x07060302u);
}
// unpack one dword holding 2 bf16 into 2 f32
__device__ __forceinline__ float bflo(unsigned d) { return __uint_as_float(d << 16); }
__device__ __forceinline__ float bfhi(unsigned d) { return __uint_as_float(d & 0xffff0000u); }

// ---------------- combined prep ----------------
// blocks 0..767: wfrag for g-GEMMs (196608 u16)
// blocks 768..878: wt1 (648 f32) + wcfrag (27648 u16)
__global__ __launch_bounds__(256) void prep_all(
    const float* __restrict__ g2w, const float* __restrict__ g3w,
    const float* __restrict__ g4w, u16* __restrict__ wfrag,
    const float* __restrict__ cw1, const float* __restrict__ cw2,
    const float* __restrict__ cw3, const float* __restrict__ cw4,
    float* __restrict__ wt1, u16* __restrict__ wcfrag)
{
    if (blockIdx.x < 768) {
        int idx = blockIdx.x * 256 + threadIdx.x;   // 196608 total
        int jj = idx & 7;
        int lane = (idx >> 3) & 63;
        int tn = (idx >> 9) & 15;
        int c = (idx >> 13) & 7;
        int l = idx >> 16;
        const float* W = (l == 0) ? g2w : ((l == 1) ? g3w : g4w);
        int n = tn * 16 + (lane & 15);
        int k = c * 32 + (lane >> 4) * 8 + jj;
        wfrag[idx] = f2bf(W[n * 256 + k]);
    } else {
        int idx = (blockIdx.x - 768) * 256 + threadIdx.x;
        if (idx < 648) {
            int k = idx / 24, oc = idx % 24;
            wt1[idx] = cw1[oc * 27 + k];
        } else if (idx < 648 + 27648) {
            int t = idx - 648;
            int l = t / 9216, r = t % 9216;
            int cell = r / 1024, rr = r % 1024;
            int o = rr / 512, q = rr % 512;
            int lane = q / 8, j = q % 8;
            int oc = o * 16 + (lane & 15);
            int ic = (lane >> 4) * 8 + j;
            const float* w = (l == 0) ? cw2 : ((l == 1) ? cw3 : cw4);
            u16 v = 0;
            if (oc < 24 && ic < 24) v = f2bf(w[oc * 216 + ic * 9 + cell]);
            wcfrag[t] = v;
        }
    }
}

// ---------------- conv1: img NCHW -> y1 channel-last, scalar-cached weights, + BN stats ----------------
__global__ __launch_bounds__(256) void conv1_t(
    const float* __restrict__ img, const float* __restrict__ wt1,
    const float* __restrict__ bias, float* __restrict__ yout,
    float* __restrict__ stats)
{
    __shared__ float tile[3 * 21 * 85];
    __shared__ float part[48];
    const int tid = threadIdx.x;
    const int b   = blockIdx.x >> 2;
    const int y0  = (blockIdx.x & 3) * 10;
    const int iy_base = 2 * y0 - 1;
    for (int e = tid; e < 3 * 21 * 85; e += 256) {
        int ixt = e % 85; int rem = e / 85;
        int iyl = rem % 21; int ic = rem / 21;
        int iy = iy_base + iyl, ix = ixt - 1;
        float v = 0.f;
        if ((unsigned)iy < 80u && (unsigned)ix < 80u)
            v = img[((size_t)(b * 3 + ic) * 80 + iy) * 80 + ix];
        tile[e] = v;
    }
    if (tid < 48) part[tid] = 0.f;
    __syncthreads();

    float rsum[24], rsq[24];
#pragma unroll
    for (int oc = 0; oc < 24; oc++) { rsum[oc] = 0.f; rsq[oc] = 0.f; }

#pragma unroll 1
    for (int pp = 0; pp < 2; pp++) {
        const int pxl = tid + pp * 256;
        const bool active = pxl < 400;
        const int pxc = active ? pxl : 0;
        const int yl = pxc / 40, x = pxc % 40;
        float acc[24];
#pragma unroll
        for (int oc = 0; oc < 24; oc++) acc[oc] = bias[oc];
#pragma unroll 1
        for (int ic = 0; ic < 3; ic++) {
#pragma unroll 1
            for (int ky = 0; ky < 3; ky++) {
#pragma unroll 1
                for (int kx = 0; kx < 3; kx++) {
                    const int k = (ic * 3 + ky) * 3 + kx;
                    float xin = tile[ic * 1785 + (2 * yl + ky) * 85 + (2 * x + kx)];
                    const float4* wrow = (const float4*)&wt1[k * 24];   // uniform -> s_load
#pragma unroll
                    for (int g = 0; g < 6; g++) {
                        float4 wv = wrow[g];
                        acc[g * 4 + 0] = fmaf(xin, wv.x, acc[g * 4 + 0]);
                        acc[g * 4 + 1] = fmaf(xin, wv.y, acc[g * 4 + 1]);
                        acc[g * 4 + 2] = fmaf(xin, wv.z, acc[g * 4 + 2]);
                        acc[g * 4 + 3] = fmaf(xin, wv.w, acc[g * 4 + 3]);
                    }
                }
            }
        }
#pragma unroll
        for (int oc = 0; oc < 24; oc++)
            acc[oc] = active ? fmaxf(acc[oc], 0.f) : 0.f;
        if (active) {
            float* op = &yout[((size_t)b * 1600 + (y0 + yl) * 40 + x) * 24];
#pragma unroll
            for (int g = 0; g < 6; g++)
                *(float4*)&op[g * 4] = make_float4(acc[g * 4], acc[g * 4 + 1],
                                                   acc[g * 4 + 2], acc[g * 4 + 3]);
        }
#pragma unroll
        for (int oc = 0; oc < 24; oc++) {
            rsum[oc] += acc[oc];
            rsq[oc]  += acc[oc] * acc[oc];
        }
    }
#pragma unroll
    for (int oc = 0; oc < 24; oc++) {
        float a = rsum[oc], q = rsq[oc];
#pragma unroll
        for (int off = 1; off < 64; off <<= 1) {
            a += __shfl_xor(a, off, 64);
            q += __shfl_xor(q, off, 64);
        }
        if ((tid & 63) == 0) { atomicAdd(&part[oc], a); atomicAdd(&part[24 + oc], q); }
    }
    __syncthreads();
    if (tid < 48) atomicAdd(&stats[tid], part[tid]);
}

// ---------------- MFMA conv 24->24 stride2 pad1 ----------------
template<int HIN, int HOUT, int YT, int MT>
__global__ __launch_bounds__(256) void convM(
    const float* __restrict__ yin,
    const float* __restrict__ stp, const float* __restrict__ gam,
    const float* __restrict__ bet, float invN,
    const u16* __restrict__ wcf_g,
    const float* __restrict__ bias,
    float* __restrict__ yout, float* __restrict__ stats)
{
    constexpr int ROWS = 2 * YT + 1;
    constexpr int R    = 2 * HOUT + 1;
    constexpr int POS  = ROWS * R;
    constexpr int NPX  = HOUT * HOUT;
    constexpr int NPXB = YT * HOUT;
    constexpr int TILES = HOUT / YT;
    constexpr int MTPW = (MT + 3) / 4;
    __shared__ __align__(16) u16 tile[POS * 24 + 16];
    __shared__ float scW[48];
    __shared__ float part[48];
    const int tid  = threadIdx.x;
    const int b    = (TILES == 1) ? blockIdx.x : (int)(blockIdx.x / TILES);
    const int y0   = (TILES == 1) ? 0 : (int)(blockIdx.x % TILES) * YT;
    const int lane = tid & 63, wave = tid >> 6;
    const int r16  = lane & 15, quad = lane >> 4;

    if (tid < 24) {
        float m   = stp[tid] * invN;
        float var = stp[24 + tid] * invN - m * m;
        float inv = gam[tid] * rsqrtf(var + 1e-5f);
        scW[tid]      = inv;
        scW[24 + tid] = bet[tid] - m * inv;
    }
    if (tid < 48) part[tid] = 0.f;

    bf16x8 wcf[9][2];
#pragma unroll
    for (int c = 0; c < 9; c++)
#pragma unroll
        for (int o = 0; o < 2; o++)
            wcf[c][o] = *(const bf16x8*)&wcf_g[((c * 2 + o) * 64 + lane) * 8];

    __syncthreads();

    const int iy_base = 2 * y0 - 1;
    for (int p = tid; p < POS; p += 256) {
        int iyl = p / R, ixt = p % R;
        int iy = iy_base + iyl, ix = ixt - 1;
        unsigned w[12];
        if ((unsigned)iy < (unsigned)HIN && (unsigned)ix < (unsigned)HIN) {
            const float* ip = &yin[((size_t)b * HIN * HIN + iy * HIN + ix) * 24];
            float e[24];
#pragma unroll
            for (int c = 0; c < 24; c++)
                e[c] = fmaf(ip[c], scW[c], scW[24 + c]);
#pragma unroll
            for (int i = 0; i < 12; i++)
                w[i] = pk2bf(e[2 * i + 1], e[2 * i]);
        } else {
#pragma unroll
            for (int i = 0; i < 12; i++) w[i] = 0;
        }
#pragma unroll
        for (int g = 0; g < 3; g++)
            *(uint4*)&tile[p * 24 + g * 8] =
                make_uint4(w[g * 4], w[g * 4 + 1], w[g * 4 + 2], w[g * 4 + 3]);
    }
    __syncthreads();

    f32x4 acc[MTPW][2];
#pragma unroll
    for (int t = 0; t < MTPW; t++) {
        acc[t][0] = (f32x4)(0.f);
        acc[t][1] = (f32x4)(0.f);
    }

    int baseT[MTPW];
#pragma unroll
    for (int t = 0; t < MTPW; t++) {
        int mt = wave + t * 4;
        int pxl = mt * 16 + r16;
        if (pxl > NPXB - 1) pxl = NPXB - 1;
        baseT[t] = ((2 * (pxl / HOUT)) * R + 2 * (pxl % HOUT)) * 24 + quad * 8;
    }

#pragma unroll
    for (int ky = 0; ky < 3; ky++) {
#pragma unroll
        for (int kx = 0; kx < 3; kx++) {
            const int cell = ky * 3 + kx;
            const int coff = (ky * R + kx) * 24;
            bf16x8 xf[MTPW];
#pragma unroll
            for (int t = 0; t < MTPW; t++) {
                int mt = wave + t * 4;
                uint4 tmp = make_uint4(0, 0, 0, 0);
                if (mt < MT && quad < 3)
                    tmp = *(const uint4*)&tile[baseT[t] + coff];
                xf[t] = *(bf16x8*)&tmp;
            }
#pragma unroll
            for (int t = 0; t < MTPW; t++) {
                int mt = wave + t * 4;
                if (mt < MT) {
                    acc[t][0] = __builtin_amdgcn_mfma_f32_16x16x32_bf16(
                        wcf[cell][0], xf[t], acc[t][0], 0, 0, 0);
                    acc[t][1] = __builtin_amdgcn_mfma_f32_16x16x32_bf16(
                        wcf[cell][1], xf[t], acc[t][1], 0, 0, 0);
                }
            }
        }
    }

    float ss[2][4], qq[2][4];
#pragma unroll
    for (int o = 0; o < 2; o++)
#pragma unroll
        for (int r = 0; r < 4; r++) { ss[o][r] = 0.f; qq[o][r] = 0.f; }

#pragma unroll
    for (int t = 0; t < MTPW; t++) {
        int mt = wave + t * 4;
        if (mt >= MT) continue;
        int pxl = mt * 16 + r16;
        bool pv = pxl < NPXB;
        int pxi = y0 * HOUT + pxl;
#pragma unroll
        for (int o = 0; o < 2; o++) {
            int ocb = o * 16 + quad * 4;
            if (pv && ocb < 24) {
                float4 bb = *(const float4*)&bias[ocb];
                float v0 = fmaxf(acc[t][o][0] + bb.x, 0.f);
                float v1 = fmaxf(acc[t][o][1] + bb.y, 0.f);
                float v2 = fmaxf(acc[t][o][2] + bb.z, 0.f);
                float v3 = fmaxf(acc[t][o][3] + bb.w, 0.f);
                *(float4*)&yout[((size_t)b * NPX + pxi) * 24 + ocb] =
                    make_float4(v0, v1, v2, v3);
                ss[o][0] += v0; qq[o][0] += v0 * v0;
                ss[o][1] += v1; qq[o][1] += v1 * v1;
                ss[o][2] += v2; qq[o][2] += v2 * v2;
                ss[o][3] += v3; qq[o][3] += v3 * v3;
            }
        }
    }
#pragma unroll
    for (int o = 0; o < 2; o++) {
        int ocb = o * 16 + quad * 4;
#pragma unroll
        for (int r = 0; r < 4; r++) {
            float a = ss[o][r], q = qq[o][r];
            a += __shfl_xor(a, 1, 64); q += __shfl_xor(q, 1, 64);
            a += __shfl_xor(a, 2, 64); q += __shfl_xor(q, 2, 64);
            a += __shfl_xor(a, 4, 64); q += __shfl_xor(q, 4, 64);
            a += __shfl_xor(a, 8, 64); q += __shfl_xor(q, 8, 64);
            if (r16 == 0 && ocb < 24) {
                atomicAdd(&part[ocb + r], a);
                atomicAdd(&part[24 + ocb + r], q);
            }
        }
    }
    __syncthreads();
    if (tid < 48) atomicAdd(&stats[tid], part[tid]);
}

// ---------------- u/v precompute for g1 (bf16 output), BN4 computed in-kernel ----------------
__global__ __launch_bounds__(256) void uv_kernel(
    const float* __restrict__ y4t,
    const float* __restrict__ stp, const float* __restrict__ gam,
    const float* __restrict__ bet, float invN,
    const float* __restrict__ qst, const float* __restrict__ g1w,
    const float* __restrict__ g1b, u16* __restrict__ u, u16* __restrict__ v)
{
    int b = blockIdx.x, tid = threadIdx.x;
    __shared__ float xf[650];
    __shared__ float qv[11];
    __shared__ float scW[48];
    if (tid < 24) {
        float m   = stp[tid] * invN;
        float var = stp[24 + tid] * invN - m * m;
        float inv = gam[tid] * rsqrtf(var + 1e-5f);
        scW[tid]      = inv;
        scW[24 + tid] = bet[tid] - m * inv;
    }
    __syncthreads();
    for (int e = tid; e < 650; e += 256) {
        int o = e / 26, c = e % 26;
        float val;
        if (c < 24)      val = y4t[b * 600 + o * 24 + c] * scW[c] + scW[24 + c];
        else if (c == 24) val = (float)(o / 5 - 2) * 0.5f;
        else              val = (float)(o % 5 - 2) * 0.5f;
        xf[e] = val;
    }
    if (tid < 11) qv[tid] = qst[tid * MB + b];
    __syncthreads();
    const int n = tid;
    float wrow[63];
#pragma unroll
    for (int c = 0; c < 63; c++) wrow[c] = g1w[n * 63 + c];
    float qsum = g1b[n];
#pragma unroll
    for (int j = 0; j < 11; j++) qsum += wrow[52 + j] * qv[j];
    for (int o = 0; o < 25; o++) {
        float uu = 0.f, vv = qsum;
#pragma unroll
        for (int c = 0; c < 26; c++) {
            uu += wrow[c]      * xf[o * 26 + c];
            vv += wrow[26 + c] * xf[o * 26 + c];
        }
        u[(b * 25 + o) * 256 + n] = f2bf(uu);
        v[(b * 25 + o) * 256 + n] = f2bf(vv);
    }
}

// ---------------- fused g2/g3/g4 + pair-sum, bf16 MFMA ----------------
// Wave split 2m x 2n: wave tile 64m x 128n (halves LDS h-read duplication; wave
// pairs share identical weight fragments -> L1 absorbs the extra W reads).
// u/v bf16 (half staging fetch), shift/and unpack + perm pack.
__global__ __launch_bounds__(256, 2) void g_fused(
    const u16* __restrict__ u_bf, const u16* __restrict__ v_bf,
    const u16* __restrict__ wfrag,
    const float* __restrict__ b2, const float* __restrict__ b3, const float* __restrict__ b4,
    float* __restrict__ xg)
{
    __shared__ u16 hS[32768];   // 128 x 256 halves, XOR-swizzled 8-half granules
    const int tid  = threadIdx.x;
    const int b    = blockIdx.x / 5;
    const int p0   = (blockIdx.x % 5) * 128;
    const int lane = tid & 63, wave = tid >> 6;
    const int r16  = lane & 15, sub = lane >> 4;
    const int m0w  = (wave & 1) * 64;
    const int n0w  = (wave >> 1) * 128;

    // weight fragment base for this wave's n-half (tn 0..7 -> global n-tile (wave>>1)*8+tn)
    const u16* wfL = wfrag + (size_t)((wave >> 1) * 8) * 512 + (size_t)lane * 8;

    // ---- stage h1 = relu(u[oi] + v[ok]) into hS (bf16 in, shift/and unpack, perm pack) ----
    {
        const int m = tid & 127, half = tid >> 7;
        const int p = p0 + m;
        if (p < 625) {
            const int oi = p % 25, ok = p / 25;
            const uint4* up = (const uint4*)(u_bf + (size_t)(b * 25 + oi) * 256);
            const uint4* vp = (const uint4*)(v_bf + (size_t)(b * 25 + ok) * 256);
#pragma unroll
            for (int gi = 0; gi < 16; gi++) {
                const int g = half * 16 + gi;
                uint4 ua = up[g], va = vp[g];
                unsigned o[4];
                {
                    const unsigned ud[4] = {ua.x, ua.y, ua.z, ua.w};
                    const unsigned vd[4] = {va.x, va.y, va.z, va.w};
#pragma unroll
                    for (int i = 0; i < 4; i++) {
                        float lo = fmaxf(bflo(ud[i]) + bflo(vd[i]), 0.f);
                        float hi = fmaxf(bfhi(ud[i]) + bfhi(vd[i]), 0.f);
                        o[i] = pk2bf(hi, lo);
                    }
                }
                *(uint4*)&hS[m * 256 + ((g ^ (m & 7)) * 8)] =
                    make_uint4(o[0], o[1], o[2], o[3]);
            }
        } else {
            uint4 z = make_uint4(0, 0, 0, 0);
#pragma unroll
            for (int gi = 0; gi < 16; gi++) {
                const int g = half * 16 + gi;
                *(uint4*)&hS[m * 256 + ((g ^ (m & 7)) * 8)] = z;
            }
        }
    }

#pragma unroll 1
    for (int l = 0; l < 3; l++) {
        f32x4 acc[4][8];
#pragma unroll
        for (int tm = 0; tm < 4; tm++)
#pragma unroll
            for (int tn = 0; tn < 8; tn++)
                acc[tm][tn] = (f32x4)(0.f);

        bf16x8 wA[8], wB[8];
#pragma unroll
        for (int tn = 0; tn < 8; tn++)
            wA[tn] = *(const bf16x8*)&wfL[((size_t)(l * 8) * 16 + tn) * 512];

        __syncthreads();   // hS ready

#pragma unroll 1
        for (int kb = 0; kb < 8; kb += 2) {
            const int s = l * 8 + kb;
            if (s + 1 < 24) {
#pragma unroll
                for (int tn = 0; tn < 8; tn++)
                    wB[tn] = *(const bf16x8*)&wfL[((size_t)(s + 1) * 16 + tn) * 512];
            }
            {
                bf16x8 bfr[4];
                const int g = kb * 4 + sub;
#pragma unroll
                for (int tm = 0; tm < 4; tm++) {
                    const int m = m0w + tm * 16 + r16;
                    bfr[tm] = *(const bf16x8*)&hS[m * 256 + ((g ^ (m & 7)) * 8)];
                }
#pragma unroll
                for (int tm = 0; tm < 4; tm++)
#pragma unroll
                    for (int tn = 0; tn < 8; tn++)
                        acc[tm][tn] = __builtin_amdgcn_mfma_f32_16x16x32_bf16(
                            wA[tn], bfr[tm], acc[tm][tn], 0, 0, 0);
            }
            if (s + 2 < 24) {
#pragma unroll
                for (int tn = 0; tn < 8; tn++)
                    wA[tn] = *(const bf16x8*)&wfL[((size_t)(s + 2) * 16 + tn) * 512];
            }
            {
                bf16x8 bfr[4];
                const int g = (kb + 1) * 4 + sub;
#pragma unroll
                for (int tm = 0; tm < 4; tm++) {
                    const int m = m0w + tm * 16 + r16;
                    bfr[tm] = *(const bf16x8*)&hS[m * 256 + ((g ^ (m & 7)) * 8)];
                }
#pragma unroll
                for (int tm = 0; tm < 4; tm++)
#pragma unroll
                    for (int tn = 0; tn < 8; tn++)
                        acc[tm][tn] = __builtin_amdgcn_mfma_f32_16x16x32_bf16(
                            wB[tn], bfr[tm], acc[tm][tn], 0, 0, 0);
            }
        }
        __syncthreads();   // all hS reads complete before overwrite

        const float* bl = (l == 0) ? b2 : ((l == 1) ? b3 : b4);
        if (l < 2) {
#pragma unroll
            for (int tn = 0; tn < 8; tn++) {
                const int n0 = n0w + tn * 16 + sub * 4;
                const float4 bb = *(const float4*)&bl[n0];
                const int gg = n0 >> 3;
                const int sh = (sub & 1) * 4;
#pragma unroll
                for (int tm = 0; tm < 4; tm++) {
                    const int m = m0w + tm * 16 + r16;
                    float v0 = fmaxf(acc[tm][tn][0] + bb.x, 0.f);
                    float v1 = fmaxf(acc[tm][tn][1] + bb.y, 0.f);
                    float v2 = fmaxf(acc[tm][tn][2] + bb.z, 0.f);
                    float v3 = fmaxf(acc[tm][tn][3] + bb.w, 0.f);
                    uint2 pw = make_uint2(pk2bf(v1, v0), pk2bf(v3, v2));
                    *(uint2*)&hS[m * 256 + ((gg ^ (m & 7)) * 8) + sh] = pw;
                }
            }
        } else {
            float s[8][4];
#pragma unroll
            for (int tn = 0; tn < 8; tn++)
#pragma unroll
                for (int r = 0; r < 4; r++) s[tn][r] = 0.f;
#pragma unroll
            for (int tn = 0; tn < 8; tn++) {
                const int n0 = n0w + tn * 16 + sub * 4;
                const float4 bb = *(const float4*)&bl[n0];
#pragma unroll
                for (int tm = 0; tm < 4; tm++) {
                    const int m = m0w + tm * 16 + r16;
                    if (p0 + m < 625) {
                        s[tn][0] += fmaxf(acc[tm][tn][0] + bb.x, 0.f);
                        s[tn][1] += fmaxf(acc[tm][tn][1] + bb.y, 0.f);
                        s[tn][2] += fmaxf(acc[tm][tn][2] + bb.z, 0.f);
                        s[tn][3] += fmaxf(acc[tm][tn][3] + bb.w, 0.f);
                    }
                }
            }
#pragma unroll
            for (int tn = 0; tn < 8; tn++)
#pragma unroll
                for (int r = 0; r < 4; r++) {
                    float v = s[tn][r];
                    v += __shfl_xor(v, 1, 64);
                    v += __shfl_xor(v, 2, 64);
                    v += __shfl_xor(v, 4, 64);
                    v += __shfl_xor(v, 8, 64);
                    if (r16 == 0)
                        atomicAdd(&xg[b * 256 + n0w + tn * 16 + sub * 4 + r], v);
                }
        }
    }
}

// ---------------- f1 -> fc2 -> fc3 -> log_softmax ----------------
__global__ __launch_bounds__(256) void f_fused(
    const float* __restrict__ xg,
    const float* __restrict__ f1w, const float* __restrict__ f1b,
    const float* __restrict__ fc2w, const float* __restrict__ fc2b,
    const float* __restrict__ fc3w, const float* __restrict__ fc3b,
    float* __restrict__ out)
{
    const int b = blockIdx.x, tid = threadIdx.x;
    __shared__ float xa[256], xb[256], lg[10], red[2];
    xa[tid] = xg[b * 256 + tid];
    __syncthreads();
    {
        const float4* wr = (const float4*)(f1w + (size_t)tid * 256);
        float a = f1b[tid];
#pragma unroll
        for (int k4 = 0; k4 < 64; k4++) {
            float4 w4 = wr[k4];
            a += w4.x * xa[k4 * 4 + 0] + w4.y * xa[k4 * 4 + 1]
               + w4.z * xa[k4 * 4 + 2] + w4.w * xa[k4 * 4 + 3];
        }
        xb[tid] = a > 0.f ? a : 0.f;
    }
    __syncthreads();
    {
        const float4* wr = (const float4*)(fc2w + (size_t)tid * 256);
        float a = fc2b[tid];
#pragma unroll
        for (int k4 = 0; k4 < 64; k4++) {
            float4 w4 = wr[k4];
            a += w4.x * xb[k4 * 4 + 0] + w4.y * xb[k4 * 4 + 1]
               + w4.z * xb[k4 * 4 + 2] + w4.w * xb[k4 * 4 + 3];
        }
        __syncthreads();
        xa[tid] = a > 0.f ? a : 0.f;
    }
    __syncthreads();
    if (tid < 10) {
        const float4* wr = (const float4*)(fc3w + (size_t)tid * 256);
        float a = fc3b[tid];
#pragma unroll
        for (int k4 = 0; k4 < 64; k4++) {
            float4 w4 = wr[k4];
            a += w4.x * xa[k4 * 4 + 0] + w4.y * xa[k4 * 4 + 1]
               + w4.z * xa[k4 * 4 + 2] + w4.w * xa[k4 * 4 + 3];
        }
        lg[tid] = a;
    }
    __syncthreads();
    if (tid == 0) {
        float mx = lg[0];
        for (int o = 1; o < 10; o++) mx = lg[o] > mx ? lg[o] : mx;
        float ssum = 0.f;
        for (int o = 0; o < 10; o++) ssum += expf(lg[o] - mx);
        red[0] = mx;
        red[1] = logf(ssum);
    }
    __syncthreads();
    if (tid < 10) out[b * 10 + tid] = lg[tid] - red[0] - red[1];
}

// ---------------- launcher ----------------
extern "C" void kernel_launch(void* const* d_in, const int* in_sizes, int n_in,
                              void* d_out, int out_size, void* d_ws, size_t ws_size,
                              hipStream_t stream)
{
    const float* img  = (const float*)d_in[0];
    const float* qst  = (const float*)d_in[1];
    const float* cw1  = (const float*)d_in[2];
    const float* cb1  = (const float*)d_in[3];
    const float* bg1  = (const float*)d_in[4];
    const float* bb1  = (const float*)d_in[5];
    const float* cw2  = (const float*)d_in[6];
    const float* cb2  = (const float*)d_in[7];
    const float* bg2  = (const float*)d_in[8];
    const float* bb2  = (const float*)d_in[9];
    const float* cw3  = (const float*)d_in[10];
    const float* cb3  = (const float*)d_in[11];
    const float* bg3  = (const float*)d_in[12];
    const float* bb3  = (const float*)d_in[13];
    const float* cw4  = (const float*)d_in[14];
    const float* cb4  = (const float*)d_in[15];
    const float* bg4  = (const float*)d_in[16];
    const float* bb4  = (const float*)d_in[17];
    const float* g1w  = (const float*)d_in[18];
    const float* g1b  = (const float*)d_in[19];
    const float* g2w  = (const float*)d_in[20];
    const float* g2b  = (const float*)d_in[21];
    const float* g3w  = (const float*)d_in[22];
    const float* g3b  = (const float*)d_in[23];
    const float* g4w  = (const float*)d_in[24];
    const float* g4b  = (const float*)d_in[25];
    const float* f1w  = (const float*)d_in[26];
    const float* f1b  = (const float*)d_in[27];
    const float* fc2w = (const float*)d_in[28];
    const float* fc2b = (const float*)d_in[29];
    const float* fc3w = (const float*)d_in[30];
    const float* fc3b = (const float*)d_in[31];
    float* out = (float*)d_out;

    float* ws    = (float*)d_ws;
    float* stats = ws;                        // 192
    float* xg    = ws + 192;                  // 131072
    u16*   wfrag = (u16*)(ws + 131456);       // 196608 u16 -> ends 229760
    float* wt1   = ws + 229760;               // 648
    u16*   wcfrag = (u16*)(ws + 230408);      // 27648 u16 -> ends 244232
    float* y1    = ws + 328064;               // 19,660,800  [b][1600][24]
    float* y2    = ws + 19988864;             // 4,915,200   [b][400][24]
    float* y3    = ws + 24904064;             // 1,228,800   [b][100][24]
    float* y4    = ws + 26132864;             // 307,200     [b][25][24]
    u16*   u_bf  = (u16*)(ws + 26440064);     // 3,276,800 u16
    u16*   v_bf  = (u16*)(ws + 28078464);     // 3,276,800 u16

    hipMemsetAsync(stats, 0, (size_t)131264 * sizeof(float), stream);

    prep_all<<<879, 256, 0, stream>>>(g2w, g3w, g4w, wfrag,
                                      cw1, cw2, cw3, cw4, wt1, wcfrag);

    conv1_t<<<2048, 256, 0, stream>>>(img, wt1, cb1, y1, stats);

    convM<40, 20, 4, 5><<<2560, 256, 0, stream>>>(
        y1, stats, bg1, bb1, 1.f / 819200.f, wcfrag, cb2, y2, stats + 48);
    convM<20, 10, 10, 7><<<512, 256, 0, stream>>>(
        y2, stats + 48, bg2, bb2, 1.f / 204800.f, wcfrag + 9216, cb3, y3, stats + 96);
    convM<10, 5, 5, 2><<<512, 256, 0, stream>>>(
        y3, stats + 96, bg3, bb3, 1.f / 51200.f, wcfrag + 18432, cb4, y4, stats + 144);

    uv_kernel<<<512, 256, 0, stream>>>(y4, stats + 144, bg4, bb4, 1.f / 12800.f,
                                       qst, g1w, g1b, u_bf, v_bf);

    g_fused<<<2560, 256, 0, stream>>>(u_bf, v_bf, wfrag, g2b, g3b, g4b, xg);

    f_fused<<<512, 256, 0, stream>>>(xg, f1w, f1b, fc2w, fc2b, fc3w, fc3b, out);
}

// Round 10
// 525.250 us; speedup vs baseline: 1.0269x; 1.0224x over previous
//
#include <hip/hip_runtime.h>
#include <math.h>

// ---------------- problem constants ----------------
#define MB    512
#define FS    24
#define QDIM  11
#define OBJ   25
#define HID   256

typedef unsigned short u16;
typedef __attribute__((ext_vector_type(8))) __bf16 bf16x8;
typedef __attribute__((ext_vector_type(4))) float f32x4;

__device__ __forceinline__ float bf2f(u16 h) {
    return __uint_as_float(((unsigned int)h) << 16);
}
__device__ __forceinline__ u16 f2bf(float f) {
    unsigned int u = __float_as_uint(f);
    return (u16)((u + 0x7FFFu + ((u >> 16) & 1u)) >> 16);
}
// pack 2 f32 -> 2 bf16 (truncate) in one v_perm_b32
__device__ __forceinline__ unsigned pk2bf(float hi, float lo) {
    return __builtin_amdgcn_perm(__float_as_uint(hi), __float_as_uint(lo), 0x07060302u);
}
// unpack one dword holding 2 bf16 into 2 f32
__device__ __forceinline__ float bflo(unsigned d) { return __uint_as_float(d << 16); }
__device__ __forceinline__ float bfhi(unsigned d) { return __uint_as_float(d & 0xffff0000u); }

// ---------------- combined prep ----------------
// blocks 0..767: wfrag for g-GEMMs (196608 u16)
// blocks 768..878: wt1 (648 f32) + wcfrag (27648 u16)
__global__ __launch_bounds__(256) void prep_all(
    const float* __restrict__ g2w, const float* __restrict__ g3w,
    const float* __restrict__ g4w, u16* __restrict__ wfrag,
    const float* __restrict__ cw1, const float* __restrict__ cw2,
    const float* __restrict__ cw3, const float* __restrict__ cw4,
    float* __restrict__ wt1, u16* __restrict__ wcfrag)
{
    if (blockIdx.x < 768) {
        int idx = blockIdx.x * 256 + threadIdx.x;   // 196608 total
        int jj = idx & 7;
        int lane = (idx >> 3) & 63;
        int tn = (idx >> 9) & 15;
        int c = (idx >> 13) & 7;
        int l = idx >> 16;
        const float* W = (l == 0) ? g2w : ((l == 1) ? g3w : g4w);
        int n = tn * 16 + (lane & 15);
        int k = c * 32 + (lane >> 4) * 8 + jj;
        wfrag[idx] = f2bf(W[n * 256 + k]);
    } else {
        int idx = (blockIdx.x - 768) * 256 + threadIdx.x;
        if (idx < 648) {
            int k = idx / 24, oc = idx % 24;
            wt1[idx] = cw1[oc * 27 + k];
        } else if (idx < 648 + 27648) {
            int t = idx - 648;
            int l = t / 9216, r = t % 9216;
            int cell = r / 1024, rr = r % 1024;
            int o = rr / 512, q = rr % 512;
            int lane = q / 8, j = q % 8;
            int oc = o * 16 + (lane & 15);
            int ic = (lane >> 4) * 8 + j;
            const float* w = (l == 0) ? cw2 : ((l == 1) ? cw3 : cw4);
            u16 v = 0;
            if (oc < 24 && ic < 24) v = f2bf(w[oc * 216 + ic * 9 + cell]);
            wcfrag[t] = v;
        }
    }
}

// ---------------- conv1: img NCHW -> y1 channel-last, scalar-cached weights, + BN stats ----------------
__global__ __launch_bounds__(256) void conv1_t(
    const float* __restrict__ img, const float* __restrict__ wt1,
    const float* __restrict__ bias, float* __restrict__ yout,
    float* __restrict__ stats)
{
    __shared__ float tile[3 * 21 * 85];
    __shared__ float part[48];
    const int tid = threadIdx.x;
    const int b   = blockIdx.x >> 2;
    const int y0  = (blockIdx.x & 3) * 10;
    const int iy_base = 2 * y0 - 1;
    for (int e = tid; e < 3 * 21 * 85; e += 256) {
        int ixt = e % 85; int rem = e / 85;
        int iyl = rem % 21; int ic = rem / 21;
        int iy = iy_base + iyl, ix = ixt - 1;
        float v = 0.f;
        if ((unsigned)iy < 80u && (unsigned)ix < 80u)
            v = img[((size_t)(b * 3 + ic) * 80 + iy) * 80 + ix];
        tile[e] = v;
    }
    if (tid < 48) part[tid] = 0.f;
    __syncthreads();

    float rsum[24], rsq[24];
#pragma unroll
    for (int oc = 0; oc < 24; oc++) { rsum[oc] = 0.f; rsq[oc] = 0.f; }

#pragma unroll 1
    for (int pp = 0; pp < 2; pp++) {
        const int pxl = tid + pp * 256;
        const bool active = pxl < 400;
        const int pxc = active ? pxl : 0;
        const int yl = pxc / 40, x = pxc % 40;
        float acc[24];
#pragma unroll
        for (int oc = 0; oc < 24; oc++) acc[oc] = bias[oc];
#pragma unroll 1
        for (int ic = 0; ic < 3; ic++) {
#pragma unroll 1
            for (int ky = 0; ky < 3; ky++) {
#pragma unroll 1
                for (int kx = 0; kx < 3; kx++) {
                    const int k = (ic * 3 + ky) * 3 + kx;
                    float xin = tile[ic * 1785 + (2 * yl + ky) * 85 + (2 * x + kx)];
                    const float4* wrow = (const float4*)&wt1[k * 24];   // uniform -> s_load
#pragma unroll
                    for (int g = 0; g < 6; g++) {
                        float4 wv = wrow[g];
                        acc[g * 4 + 0] = fmaf(xin, wv.x, acc[g * 4 + 0]);
                        acc[g * 4 + 1] = fmaf(xin, wv.y, acc[g * 4 + 1]);
                        acc[g * 4 + 2] = fmaf(xin, wv.z, acc[g * 4 + 2]);
                        acc[g * 4 + 3] = fmaf(xin, wv.w, acc[g * 4 + 3]);
                    }
                }
            }
        }
#pragma unroll
        for (int oc = 0; oc < 24; oc++)
            acc[oc] = active ? fmaxf(acc[oc], 0.f) : 0.f;
        if (active) {
            float* op = &yout[((size_t)b * 1600 + (y0 + yl) * 40 + x) * 24];
#pragma unroll
            for (int g = 0; g < 6; g++)
                *(float4*)&op[g * 4] = make_float4(acc[g * 4], acc[g * 4 + 1],
                                                   acc[g * 4 + 2], acc[g * 4 + 3]);
        }
#pragma unroll
        for (int oc = 0; oc < 24; oc++) {
            rsum[oc] += acc[oc];
            rsq[oc]  += acc[oc] * acc[oc];
        }
    }
#pragma unroll
    for (int oc = 0; oc < 24; oc++) {
        float a = rsum[oc], q = rsq[oc];
#pragma unroll
        for (int off = 1; off < 64; off <<= 1) {
            a += __shfl_xor(a, off, 64);
            q += __shfl_xor(q, off, 64);
        }
        if ((tid & 63) == 0) { atomicAdd(&part[oc], a); atomicAdd(&part[24 + oc], q); }
    }
    __syncthreads();
    if (tid < 48) atomicAdd(&stats[tid], part[tid]);
}

// ---------------- MFMA conv 24->24 stride2 pad1 ----------------
template<int HIN, int HOUT, int YT, int MT>
__global__ __launch_bounds__(256) void convM(
    const float* __restrict__ yin,
    const float* __restrict__ stp, const float* __restrict__ gam,
    const float* __restrict__ bet, float invN,
    const u16* __restrict__ wcf_g,
    const float* __restrict__ bias,
    float* __restrict__ yout, float* __restrict__ stats)
{
    constexpr int ROWS = 2 * YT + 1;
    constexpr int R    = 2 * HOUT + 1;
    constexpr int POS  = ROWS * R;
    constexpr int NPX  = HOUT * HOUT;
    constexpr int NPXB = YT * HOUT;
    constexpr int TILES = HOUT / YT;
    constexpr int MTPW = (MT + 3) / 4;
    __shared__ __align__(16) u16 tile[POS * 24 + 16];
    __shared__ float scW[48];
    __shared__ float part[48];
    const int tid  = threadIdx.x;
    const int b    = (TILES == 1) ? blockIdx.x : (int)(blockIdx.x / TILES);
    const int y0   = (TILES == 1) ? 0 : (int)(blockIdx.x % TILES) * YT;
    const int lane = tid & 63, wave = tid >> 6;
    const int r16  = lane & 15, quad = lane >> 4;

    if (tid < 24) {
        float m   = stp[tid] * invN;
        float var = stp[24 + tid] * invN - m * m;
        float inv = gam[tid] * rsqrtf(var + 1e-5f);
        scW[tid]      = inv;
        scW[24 + tid] = bet[tid] - m * inv;
    }
    if (tid < 48) part[tid] = 0.f;

    bf16x8 wcf[9][2];
#pragma unroll
    for (int c = 0; c < 9; c++)
#pragma unroll
        for (int o = 0; o < 2; o++)
            wcf[c][o] = *(const bf16x8*)&wcf_g[((c * 2 + o) * 64 + lane) * 8];

    __syncthreads();

    const int iy_base = 2 * y0 - 1;
    for (int p = tid; p < POS; p += 256) {
        int iyl = p / R, ixt = p % R;
        int iy = iy_base + iyl, ix = ixt - 1;
        unsigned w[12];
        if ((unsigned)iy < (unsigned)HIN && (unsigned)ix < (unsigned)HIN) {
            const float* ip = &yin[((size_t)b * HIN * HIN + iy * HIN + ix) * 24];
            float e[24];
#pragma unroll
            for (int c = 0; c < 24; c++)
                e[c] = fmaf(ip[c], scW[c], scW[24 + c]);
#pragma unroll
            for (int i = 0; i < 12; i++)
                w[i] = pk2bf(e[2 * i + 1], e[2 * i]);
        } else {
#pragma unroll
            for (int i = 0; i < 12; i++) w[i] = 0;
        }
#pragma unroll
        for (int g = 0; g < 3; g++)
            *(uint4*)&tile[p * 24 + g * 8] =
                make_uint4(w[g * 4], w[g * 4 + 1], w[g * 4 + 2], w[g * 4 + 3]);
    }
    __syncthreads();

    f32x4 acc[MTPW][2];
#pragma unroll
    for (int t = 0; t < MTPW; t++) {
        acc[t][0] = (f32x4)(0.f);
        acc[t][1] = (f32x4)(0.f);
    }

    int baseT[MTPW];
#pragma unroll
    for (int t = 0; t < MTPW; t++) {
        int mt = wave + t * 4;
        int pxl = mt * 16 + r16;
        if (pxl > NPXB - 1) pxl = NPXB - 1;
        baseT[t] = ((2 * (pxl / HOUT)) * R + 2 * (pxl % HOUT)) * 24 + quad * 8;
    }

#pragma unroll
    for (int ky = 0; ky < 3; ky++) {
#pragma unroll
        for (int kx = 0; kx < 3; kx++) {
            const int cell = ky * 3 + kx;
            const int coff = (ky * R + kx) * 24;
            bf16x8 xf[MTPW];
#pragma unroll
            for (int t = 0; t < MTPW; t++) {
                int mt = wave + t * 4;
                uint4 tmp = make_uint4(0, 0, 0, 0);
                if (mt < MT && quad < 3)
                    tmp = *(const uint4*)&tile[baseT[t] + coff];
                xf[t] = *(bf16x8*)&tmp;
            }
#pragma unroll
            for (int t = 0; t < MTPW; t++) {
                int mt = wave + t * 4;
                if (mt < MT) {
                    acc[t][0] = __builtin_amdgcn_mfma_f32_16x16x32_bf16(
                        wcf[cell][0], xf[t], acc[t][0], 0, 0, 0);
                    acc[t][1] = __builtin_amdgcn_mfma_f32_16x16x32_bf16(
                        wcf[cell][1], xf[t], acc[t][1], 0, 0, 0);
                }
            }
        }
    }

    float ss[2][4], qq[2][4];
#pragma unroll
    for (int o = 0; o < 2; o++)
#pragma unroll
        for (int r = 0; r < 4; r++) { ss[o][r] = 0.f; qq[o][r] = 0.f; }

#pragma unroll
    for (int t = 0; t < MTPW; t++) {
        int mt = wave + t * 4;
        if (mt >= MT) continue;
        int pxl = mt * 16 + r16;
        bool pv = pxl < NPXB;
        int pxi = y0 * HOUT + pxl;
#pragma unroll
        for (int o = 0; o < 2; o++) {
            int ocb = o * 16 + quad * 4;
            if (pv && ocb < 24) {
                float4 bb = *(const float4*)&bias[ocb];
                float v0 = fmaxf(acc[t][o][0] + bb.x, 0.f);
                float v1 = fmaxf(acc[t][o][1] + bb.y, 0.f);
                float v2 = fmaxf(acc[t][o][2] + bb.z, 0.f);
                float v3 = fmaxf(acc[t][o][3] + bb.w, 0.f);
                *(float4*)&yout[((size_t)b * NPX + pxi) * 24 + ocb] =
                    make_float4(v0, v1, v2, v3);
                ss[o][0] += v0; qq[o][0] += v0 * v0;
                ss[o][1] += v1; qq[o][1] += v1 * v1;
                ss[o][2] += v2; qq[o][2] += v2 * v2;
                ss[o][3] += v3; qq[o][3] += v3 * v3;
            }
        }
    }
#pragma unroll
    for (int o = 0; o < 2; o++) {
        int ocb = o * 16 + quad * 4;
#pragma unroll
        for (int r = 0; r < 4; r++) {
            float a = ss[o][r], q = qq[o][r];
            a += __shfl_xor(a, 1, 64); q += __shfl_xor(q, 1, 64);
            a += __shfl_xor(a, 2, 64); q += __shfl_xor(q, 2, 64);
            a += __shfl_xor(a, 4, 64); q += __shfl_xor(q, 4, 64);
            a += __shfl_xor(a, 8, 64); q += __shfl_xor(q, 8, 64);
            if (r16 == 0 && ocb < 24) {
                atomicAdd(&part[ocb + r], a);
                atomicAdd(&part[24 + ocb + r], q);
            }
        }
    }
    __syncthreads();
    if (tid < 48) atomicAdd(&stats[tid], part[tid]);
}

// ---------------- u/v precompute for g1 (bf16 output), BN4 computed in-kernel ----------------
__global__ __launch_bounds__(256) void uv_kernel(
    const float* __restrict__ y4t,
    const float* __restrict__ stp, const float* __restrict__ gam,
    const float* __restrict__ bet, float invN,
    const float* __restrict__ qst, const float* __restrict__ g1w,
    const float* __restrict__ g1b, u16* __restrict__ u, u16* __restrict__ v)
{
    int b = blockIdx.x, tid = threadIdx.x;
    __shared__ float xf[650];
    __shared__ float qv[11];
    __shared__ float scW[48];
    if (tid < 24) {
        float m   = stp[tid] * invN;
        float var = stp[24 + tid] * invN - m * m;
        float inv = gam[tid] * rsqrtf(var + 1e-5f);
        scW[tid]      = inv;
        scW[24 + tid] = bet[tid] - m * inv;
    }
    __syncthreads();
    for (int e = tid; e < 650; e += 256) {
        int o = e / 26, c = e % 26;
        float val;
        if (c < 24)      val = y4t[b * 600 + o * 24 + c] * scW[c] + scW[24 + c];
        else if (c == 24) val = (float)(o / 5 - 2) * 0.5f;
        else              val = (float)(o % 5 - 2) * 0.5f;
        xf[e] = val;
    }
    if (tid < 11) qv[tid] = qst[tid * MB + b];
    __syncthreads();
    const int n = tid;
    float wrow[63];
#pragma unroll
    for (int c = 0; c < 63; c++) wrow[c] = g1w[n * 63 + c];
    float qsum = g1b[n];
#pragma unroll
    for (int j = 0; j < 11; j++) qsum += wrow[52 + j] * qv[j];
    for (int o = 0; o < 25; o++) {
        float uu = 0.f, vv = qsum;
#pragma unroll
        for (int c = 0; c < 26; c++) {
            uu += wrow[c]      * xf[o * 26 + c];
            vv += wrow[26 + c] * xf[o * 26 + c];
        }
        u[(b * 25 + o) * 256 + n] = f2bf(uu);
        v[(b * 25 + o) * 256 + n] = f2bf(vv);
    }
}

// ---------------- fused g2/g3/g4 + pair-sum, bf16 MFMA ----------------
// 64-row h-tile (32KB LDS) -> 4 blocks/CU, 4 waves/SIMD (launch_bounds 256,4).
// Wave tile 64m x 64n; weight frags from pre-permuted global (L1/L2-resident),
// ping-pong prefetch; perm-pack bf16 everywhere.
__global__ __launch_bounds__(256, 4) void g_fused(
    const u16* __restrict__ u_bf, const u16* __restrict__ v_bf,
    const u16* __restrict__ wfrag,
    const float* __restrict__ b2, const float* __restrict__ b3, const float* __restrict__ b4,
    float* __restrict__ xg)
{
    __shared__ u16 hS[16384];   // 64 x 256 halves, XOR-swizzled 8-half granules
    const int tid  = threadIdx.x;
    const int b    = blockIdx.x / 10;
    const int p0   = (blockIdx.x % 10) * 64;
    const int lane = tid & 63, wave = tid >> 6;
    const int r16  = lane & 15, sub = lane >> 4;
    const int n0w  = wave * 64;

    const u16* wfL = wfrag + (size_t)(wave * 4) * 512 + (size_t)lane * 8;

    // ---- stage h1 = relu(u[oi] + v[ok]) into hS ----
    {
        const int m = tid >> 2, q = tid & 3;
        const int p = p0 + m;
        if (p < 625) {
            const int oi = p % 25, ok = p / 25;
            const uint4* up = (const uint4*)(u_bf + (size_t)(b * 25 + oi) * 256);
            const uint4* vp = (const uint4*)(v_bf + (size_t)(b * 25 + ok) * 256);
#pragma unroll
            for (int gi = 0; gi < 8; gi++) {
                const int g = q * 8 + gi;
                uint4 ua = up[g], va = vp[g];
                unsigned o[4];
                {
                    const unsigned ud[4] = {ua.x, ua.y, ua.z, ua.w};
                    const unsigned vd[4] = {va.x, va.y, va.z, va.w};
#pragma unroll
                    for (int i = 0; i < 4; i++) {
                        float lo = fmaxf(bflo(ud[i]) + bflo(vd[i]), 0.f);
                        float hi = fmaxf(bfhi(ud[i]) + bfhi(vd[i]), 0.f);
                        o[i] = pk2bf(hi, lo);
                    }
                }
                *(uint4*)&hS[m * 256 + ((g ^ (m & 7)) * 8)] =
                    make_uint4(o[0], o[1], o[2], o[3]);
            }
        } else {
            uint4 z = make_uint4(0, 0, 0, 0);
#pragma unroll
            for (int gi = 0; gi < 8; gi++) {
                const int g = q * 8 + gi;
                *(uint4*)&hS[m * 256 + ((g ^ (m & 7)) * 8)] = z;
            }
        }
    }

#pragma unroll 1
    for (int l = 0; l < 3; l++) {
        f32x4 acc[4][4];
#pragma unroll
        for (int tm = 0; tm < 4; tm++)
#pragma unroll
            for (int tn = 0; tn < 4; tn++)
                acc[tm][tn] = (f32x4)(0.f);

        bf16x8 wA[4], wB[4];
#pragma unroll
        for (int tn = 0; tn < 4; tn++)
            wA[tn] = *(const bf16x8*)&wfL[((size_t)(l * 8) * 16 + tn) * 512];

        __syncthreads();   // hS ready

#pragma unroll 1
        for (int kb = 0; kb < 8; kb += 2) {
            const int s = l * 8 + kb;
            if (s + 1 < 24) {
#pragma unroll
                for (int tn = 0; tn < 4; tn++)
                    wB[tn] = *(const bf16x8*)&wfL[((size_t)(s + 1) * 16 + tn) * 512];
            }
            {
                bf16x8 bfr[4];
                const int g = kb * 4 + sub;
#pragma unroll
                for (int tm = 0; tm < 4; tm++) {
                    const int m = tm * 16 + r16;
                    bfr[tm] = *(const bf16x8*)&hS[m * 256 + ((g ^ (m & 7)) * 8)];
                }
#pragma unroll
                for (int tm = 0; tm < 4; tm++)
#pragma unroll
                    for (int tn = 0; tn < 4; tn++)
                        acc[tm][tn] = __builtin_amdgcn_mfma_f32_16x16x32_bf16(
                            wA[tn], bfr[tm], acc[tm][tn], 0, 0, 0);
            }
            if (s + 2 < 24) {
#pragma unroll
                for (int tn = 0; tn < 4; tn++)
                    wA[tn] = *(const bf16x8*)&wfL[((size_t)(s + 2) * 16 + tn) * 512];
            }
            {
                bf16x8 bfr[4];
                const int g = (kb + 1) * 4 + sub;
#pragma unroll
                for (int tm = 0; tm < 4; tm++) {
                    const int m = tm * 16 + r16;
                    bfr[tm] = *(const bf16x8*)&hS[m * 256 + ((g ^ (m & 7)) * 8)];
                }
#pragma unroll
                for (int tm = 0; tm < 4; tm++)
#pragma unroll
                    for (int tn = 0; tn < 4; tn++)
                        acc[tm][tn] = __builtin_amdgcn_mfma_f32_16x16x32_bf16(
                            wB[tn], bfr[tm], acc[tm][tn], 0, 0, 0);
            }
        }
        __syncthreads();   // all hS reads complete before overwrite

        const float* bl = (l == 0) ? b2 : ((l == 1) ? b3 : b4);
        if (l < 2) {
#pragma unroll
            for (int tn = 0; tn < 4; tn++) {
                const int n0 = n0w + tn * 16 + sub * 4;
                const float4 bb = *(const float4*)&bl[n0];
                const int gg = n0 >> 3;
                const int sh = (sub & 1) * 4;
#pragma unroll
                for (int tm = 0; tm < 4; tm++) {
                    const int m = tm * 16 + r16;
                    float v0 = fmaxf(acc[tm][tn][0] + bb.x, 0.f);
                    float v1 = fmaxf(acc[tm][tn][1] + bb.y, 0.f);
                    float v2 = fmaxf(acc[tm][tn][2] + bb.z, 0.f);
                    float v3 = fmaxf(acc[tm][tn][3] + bb.w, 0.f);
                    uint2 pw = make_uint2(pk2bf(v1, v0), pk2bf(v3, v2));
                    *(uint2*)&hS[m * 256 + ((gg ^ (m & 7)) * 8) + sh] = pw;
                }
            }
        } else {
            float s[4][4];
#pragma unroll
            for (int tn = 0; tn < 4; tn++)
#pragma unroll
                for (int r = 0; r < 4; r++) s[tn][r] = 0.f;
#pragma unroll
            for (int tn = 0; tn < 4; tn++) {
                const int n0 = n0w + tn * 16 + sub * 4;
                const float4 bb = *(const float4*)&bl[n0];
#pragma unroll
                for (int tm = 0; tm < 4; tm++) {
                    const int m = tm * 16 + r16;
                    if (p0 + m < 625) {
                        s[tn][0] += fmaxf(acc[tm][tn][0] + bb.x, 0.f);
                        s[tn][1] += fmaxf(acc[tm][tn][1] + bb.y, 0.f);
                        s[tn][2] += fmaxf(acc[tm][tn][2] + bb.z, 0.f);
                        s[tn][3] += fmaxf(acc[tm][tn][3] + bb.w, 0.f);
                    }
                }
            }
#pragma unroll
            for (int tn = 0; tn < 4; tn++)
#pragma unroll
                for (int r = 0; r < 4; r++) {
                    float v = s[tn][r];
                    v += __shfl_xor(v, 1, 64);
                    v += __shfl_xor(v, 2, 64);
                    v += __shfl_xor(v, 4, 64);
                    v += __shfl_xor(v, 8, 64);
                    if (r16 == 0)
                        atomicAdd(&xg[b * 256 + n0w + tn * 16 + sub * 4 + r], v);
                }
        }
    }
}

// ---------------- f1 -> fc2 -> fc3 -> log_softmax ----------------
__global__ __launch_bounds__(256) void f_fused(
    const float* __restrict__ xg,
    const float* __restrict__ f1w, const float* __restrict__ f1b,
    const float* __restrict__ fc2w, const float* __restrict__ fc2b,
    const float* __restrict__ fc3w, const float* __restrict__ fc3b,
    float* __restrict__ out)
{
    const int b = blockIdx.x, tid = threadIdx.x;
    __shared__ float xa[256], xb[256], lg[10], red[2];
    xa[tid] = xg[b * 256 + tid];
    __syncthreads();
    {
        const float4* wr = (const float4*)(f1w + (size_t)tid * 256);
        float a = f1b[tid];
#pragma unroll
        for (int k4 = 0; k4 < 64; k4++) {
            float4 w4 = wr[k4];
            a += w4.x * xa[k4 * 4 + 0] + w4.y * xa[k4 * 4 + 1]
               + w4.z * xa[k4 * 4 + 2] + w4.w * xa[k4 * 4 + 3];
        }
        xb[tid] = a > 0.f ? a : 0.f;
    }
    __syncthreads();
    {
        const float4* wr = (const float4*)(fc2w + (size_t)tid * 256);
        float a = fc2b[tid];
#pragma unroll
        for (int k4 = 0; k4 < 64; k4++) {
            float4 w4 = wr[k4];
            a += w4.x * xb[k4 * 4 + 0] + w4.y * xb[k4 * 4 + 1]
               + w4.z * xb[k4 * 4 + 2] + w4.w * xb[k4 * 4 + 3];
        }
        __syncthreads();
        xa[tid] = a > 0.f ? a : 0.f;
    }
    __syncthreads();
    if (tid < 10) {
        const float4* wr = (const float4*)(fc3w + (size_t)tid * 256);
        float a = fc3b[tid];
#pragma unroll
        for (int k4 = 0; k4 < 64; k4++) {
            float4 w4 = wr[k4];
            a += w4.x * xa[k4 * 4 + 0] + w4.y * xa[k4 * 4 + 1]
               + w4.z * xa[k4 * 4 + 2] + w4.w * xa[k4 * 4 + 3];
        }
        lg[tid] = a;
    }
    __syncthreads();
    if (tid == 0) {
        float mx = lg[0];
        for (int o = 1; o < 10; o++) mx = lg[o] > mx ? lg[o] : mx;
        float ssum = 0.f;
        for (int o = 0; o < 10; o++) ssum += expf(lg[o] - mx);
        red[0] = mx;
        red[1] = logf(ssum);
    }
    __syncthreads();
    if (tid < 10) out[b * 10 + tid] = lg[tid] - red[0] - red[1];
}

// ---------------- launcher ----------------
extern "C" void kernel_launch(void* const* d_in, const int* in_sizes, int n_in,
                              void* d_out, int out_size, void* d_ws, size_t ws_size,
                              hipStream_t stream)
{
    const float* img  = (const float*)d_in[0];
    const float* qst  = (const float*)d_in[1];
    const float* cw1  = (const float*)d_in[2];
    const float* cb1  = (const float*)d_in[3];
    const float* bg1  = (const float*)d_in[4];
    const float* bb1  = (const float*)d_in[5];
    const float* cw2  = (const float*)d_in[6];
    const float* cb2  = (const float*)d_in[7];
    const float* bg2  = (const float*)d_in[8];
    const float* bb2  = (const float*)d_in[9];
    const float* cw3  = (const float*)d_in[10];
    const float* cb3  = (const float*)d_in[11];
    const float* bg3  = (const float*)d_in[12];
    const float* bb3  = (const float*)d_in[13];
    const float* cw4  = (const float*)d_in[14];
    const float* cb4  = (const float*)d_in[15];
    const float* bg4  = (const float*)d_in[16];
    const float* bb4  = (const float*)d_in[17];
    const float* g1w  = (const float*)d_in[18];
    const float* g1b  = (const float*)d_in[19];
    const float* g2w  = (const float*)d_in[20];
    const float* g2b  = (const float*)d_in[21];
    const float* g3w  = (const float*)d_in[22];
    const float* g3b  = (const float*)d_in[23];
    const float* g4w  = (const float*)d_in[24];
    const float* g4b  = (const float*)d_in[25];
    const float* f1w  = (const float*)d_in[26];
    const float* f1b  = (const float*)d_in[27];
    const float* fc2w = (const float*)d_in[28];
    const float* fc2b = (const float*)d_in[29];
    const float* fc3w = (const float*)d_in[30];
    const float* fc3b = (const float*)d_in[31];
    float* out = (float*)d_out;

    float* ws    = (float*)d_ws;
    float* stats = ws;                        // 192
    float* xg    = ws + 192;                  // 131072
    u16*   wfrag = (u16*)(ws + 131456);       // 196608 u16 -> ends 229760
    float* wt1   = ws + 229760;               // 648
    u16*   wcfrag = (u16*)(ws + 230408);      // 27648 u16 -> ends 244232
    float* y1    = ws + 328064;               // 19,660,800  [b][1600][24]
    float* y2    = ws + 19988864;             // 4,915,200   [b][400][24]
    float* y3    = ws + 24904064;             // 1,228,800   [b][100][24]
    float* y4    = ws + 26132864;             // 307,200     [b][25][24]
    u16*   u_bf  = (u16*)(ws + 26440064);     // 3,276,800 u16
    u16*   v_bf  = (u16*)(ws + 28078464);     // 3,276,800 u16

    hipMemsetAsync(stats, 0, (size_t)131264 * sizeof(float), stream);

    prep_all<<<879, 256, 0, stream>>>(g2w, g3w, g4w, wfrag,
                                      cw1, cw2, cw3, cw4, wt1, wcfrag);

    conv1_t<<<2048, 256, 0, stream>>>(img, wt1, cb1, y1, stats);

    convM<40, 20, 4, 5><<<2560, 256, 0, stream>>>(
        y1, stats, bg1, bb1, 1.f / 819200.f, wcfrag, cb2, y2, stats + 48);
    convM<20, 10, 10, 7><<<512, 256, 0, stream>>>(
        y2, stats + 48, bg2, bb2, 1.f / 204800.f, wcfrag + 9216, cb3, y3, stats + 96);
    convM<10, 5, 5, 2><<<512, 256, 0, stream>>>(
        y3, stats + 96, bg3, bb3, 1.f / 51200.f, wcfrag + 18432, cb4, y4, stats + 144);

    uv_kernel<<<512, 256, 0, stream>>>(y4, stats + 144, bg4, bb4, 1.f / 12800.f,
                                       qst, g1w, g1b, u_bf, v_bf);

    g_fused<<<5120, 256, 0, stream>>>(u_bf, v_bf, wfrag, g2b, g3b, g4b, xg);

    f_fused<<<512, 256, 0, stream>>>(xg, f1w, f1b, fc2w, fc2b, fc3w, fc3b, out);
}